// Round 8
// baseline (512.807 us; speedup 1.0000x reference)
//
#include <hip/hip_runtime.h>

typedef unsigned short u16;
typedef __attribute__((ext_vector_type(8))) short bf16x8;
typedef __attribute__((ext_vector_type(4))) float f32x4;

__device__ __forceinline__ u16 f2bf(float f) {
  unsigned u = __float_as_uint(f);
  u += 0x7FFFu + ((u >> 16) & 1u);
  return (u16)(u >> 16);
}
__device__ __forceinline__ float bf2f(u16 h) {
  return __uint_as_float(((unsigned)h) << 16);
}

#define GLOAD16(g, l) __builtin_amdgcn_global_load_lds( \
    (const __attribute__((address_space(1))) void*)(g), \
    (__attribute__((address_space(3))) void*)(l), 16, 0, 0)

// ---------- elementwise converts ----------
__global__ __launch_bounds__(256) void cvtw_kernel(const float* __restrict__ in,
                                                   u16* __restrict__ out, int n4) {
  int i = blockIdx.x * 256 + threadIdx.x;
  if (i >= n4) return;
  float4 f = ((const float4*)in)[i];
  ushort4 u;
  u.x = f2bf(f.x); u.y = f2bf(f.y); u.z = f2bf(f.z); u.w = f2bf(f.w);
  ((ushort4*)out)[i] = u;
}

// gather x rows = ((s-s0)*128 + b)*4 + m from hidden[s][m][b][0][h]
__global__ __launch_bounds__(256) void xcvt_kernel(const float* __restrict__ hidden,
                                                   u16* __restrict__ xb, int s0) {
  int idx = blockIdx.x * 256 + threadIdx.x;
  int h4 = idx & 255;
  int lrow = idx >> 8;
  int m = lrow & 3;
  int b = (lrow >> 2) & 127;
  int sl = lrow >> 9;
  int s = s0 + sl;
  const float4 f = *(const float4*)(hidden + (((size_t)(s * 4 + m) * 128 + b) * 1024) + h4 * 4);
  ushort4 u;
  u.x = f2bf(f.x); u.y = f2bf(f.y); u.z = f2bf(f.z); u.w = f2bf(f.w);
  *(ushort4*)(xb + (size_t)lrow * 1024 + h4 * 4) = u;
}

// ---------- ring-3 GEMM: BM=256 BN=128 BK=32, 4 waves, 72KB LDS, 2 blocks/CU ----------
// One barrier per K-tile; read-ahead frags with counted lgkm; ring-3 counted vmcnt(6).
// C[m,n] = sum_k A[m,k]*Bw[n,k] + bias[n]
// MODE 0: bf16 out, C[row*N+col]
// MODE 1: bf16 out, row -> s=row>>7,b=row&127; += posenc[s][col]; out[(b*64+s)*1024+col]
// MODE 2: f32 out, row -> s=row&63,b=row>>6; out[(s*128+b)*1024+col]
// Requires M%256==0, N%128==0, K%32==0, K/32>=3, grid blocks %8==0.
template <int MODE>
__global__ __launch_bounds__(256, 2) void gemm_r3(const u16* __restrict__ A,
                                                  const u16* __restrict__ Bw,
                                                  const float* __restrict__ bias,
                                                  void* __restrict__ Cout,
                                                  int N, int K,
                                                  const float* __restrict__ posenc) {
  __shared__ u16 SA[3][8192];   // 48 KB: 3 x (256 rows x 32 k)
  __shared__ u16 SB[3][4096];   // 24 KB: 3 x (128 rows x 32 k)
  const int t = threadIdx.x, w = t >> 6, l = t & 63;
  const int lr = l & 15, lg = l >> 4;
  const int wm = w >> 1, wn = w & 1;   // wave tile 128x64

  // XCD-aware bijective swizzle (grid blocks % 8 == 0)
  const int gx = gridDim.x;
  const int nb = gx * gridDim.y;
  const int id = blockIdx.y * gx + blockIdx.x;
  const int id2 = (id & 7) * (nb >> 3) + (id >> 3);
  const int rowBase = (id2 / gx) * 256, colBase = (id2 % gx) * 128;

  // staging: per call, wave w covers rows [w*16, +16); lane l -> row +(l>>2),
  // 16B slot (l&3); pre-swizzled global slot = (l&3) ^ (row&3)
  const int srow = l >> 2;
  const int ssl = ((l & 3) ^ (srow & 3)) * 8;
  const u16* Ag = A + (size_t)(rowBase + w * 16 + srow) * K + ssl;
  const u16* Bg = Bw + (size_t)(colBase + w * 16 + srow) * K + ssl;
  u16* const lA = &SA[0][0] + w * 512;
  u16* const lB = &SB[0][0] + w * 512;

  // fragment reads: row*32 + (lg ^ (row&3))*8 ; row&3 == lr&3
  const int fsw = (lg ^ (lr & 3)) * 8;
  const int aoff = (wm * 128 + lr) * 32 + fsw;
  const int boff = (wn * 64 + lr) * 32 + fsw;

  f32x4 acc[8][4];
#pragma unroll
  for (int i = 0; i < 8; i++)
#pragma unroll
    for (int j = 0; j < 4; j++) acc[i][j] = (f32x4){0.f, 0.f, 0.f, 0.f};

#define STG_P0(tt, bb) do { \
    const size_t ko_ = (size_t)(tt) * 32; \
    GLOAD16(Ag + ko_,                    lA + (bb) * 8192); \
    GLOAD16(Ag + ko_ + (size_t)64 * K,   lA + (bb) * 8192 + 2048); \
    GLOAD16(Ag + ko_ + (size_t)128 * K,  lA + (bb) * 8192 + 4096); \
  } while (0)
#define STG_P1(tt, bb) do { \
    const size_t ko_ = (size_t)(tt) * 32; \
    GLOAD16(Ag + ko_ + (size_t)192 * K,  lA + (bb) * 8192 + 6144); \
    GLOAD16(Bg + ko_,                    lB + (bb) * 4096); \
    GLOAD16(Bg + ko_ + (size_t)64 * K,   lB + (bb) * 4096 + 2048); \
  } while (0)
#define LG(NN) asm volatile("s_waitcnt lgkmcnt(" #NN ")" ::: "memory"); \
               __builtin_amdgcn_sched_barrier(0)
#define WTC(NN) asm volatile("s_waitcnt vmcnt(" #NN ")" ::: "memory")

  const int nt = K >> 5;
  // prologue: stage tiles 0,1; publish tile 0 (6 of tile 1 stay in flight)
  STG_P0(0, 0); STG_P1(0, 0);
  STG_P0(1, 1); STG_P1(1, 1);
  WTC(6);
  __builtin_amdgcn_s_barrier();

  int bcur = 0;
  for (int tt = 0; tt < nt; ++tt) {
    const u16* pa = &SA[bcur][0];
    const u16* pb = &SB[bcur][0];
    const int bnext = (bcur + 2 > 2) ? bcur - 1 : bcur + 2;  // (bcur+2)%3
    bf16x8 af[4], ag[4], bfr[4];

    // issue all 12 ds_reads up-front (8 for cluster0, 4 for cluster1),
    // interleaved with the 6 staging gloads for tile tt+2
#pragma unroll
    for (int m = 0; m < 4; m++) af[m] = *(const bf16x8*)(pa + aoff + m * 512);
#pragma unroll
    for (int n = 0; n < 4; n++) bfr[n] = *(const bf16x8*)(pb + boff + n * 512);
    if (tt + 2 < nt) STG_P0(tt + 2, bnext);
#pragma unroll
    for (int m = 0; m < 4; m++) ag[m] = *(const bf16x8*)(pa + aoff + (m + 4) * 512);
    if (tt + 2 < nt) STG_P1(tt + 2, bnext);

    LG(4);   // in-order DS: oldest 8 (af,bfr) complete; ag may still be in flight
    __builtin_amdgcn_s_setprio(1);
#pragma unroll
    for (int m = 0; m < 4; m++)
#pragma unroll
      for (int n = 0; n < 4; n++)
        acc[m][n] = __builtin_amdgcn_mfma_f32_16x16x32_bf16(af[m], bfr[n], acc[m][n], 0, 0, 0);
    __builtin_amdgcn_s_setprio(0);
    LG(0);   // ag complete (drained under the MFMA cluster above)
    __builtin_amdgcn_s_setprio(1);
#pragma unroll
    for (int m = 0; m < 4; m++)
#pragma unroll
      for (int n = 0; n < 4; n++)
        acc[m + 4][n] = __builtin_amdgcn_mfma_f32_16x16x32_bf16(ag[m], bfr[n], acc[m + 4][n], 0, 0, 0);
    __builtin_amdgcn_s_setprio(0);

    if (tt + 2 < nt) {
      WTC(6);   // force tile tt+1's 6 loads; tile tt+2's 6 stay in flight
    } else if (tt + 1 < nt) {
      WTC(0);   // tail: force tile tt+1
    }
    __builtin_amdgcn_s_barrier();   // single barrier per K-tile
    bcur = (bcur + 1 > 2) ? 0 : bcur + 1;
  }
#undef WTC
#undef LG
#undef STG_P1
#undef STG_P0

  // epilogue
  const int orow0 = rowBase + wm * 128 + lg * 4;
  const int ocol0 = colBase + wn * 64 + lr;
#pragma unroll
  for (int m = 0; m < 8; m++) {
#pragma unroll
    for (int n = 0; n < 4; n++) {
      const int col = ocol0 + n * 16;
      const float bv = bias[col];
#pragma unroll
      for (int r = 0; r < 4; r++) {
        const int row = orow0 + m * 16 + r;
        float v = acc[m][n][r] + bv;
        if (MODE == 0) {
          ((u16*)Cout)[(size_t)row * N + col] = f2bf(v);
        } else if (MODE == 1) {
          int s = row >> 7, b = row & 127;
          v += posenc[s * 1024 + col];
          ((u16*)Cout)[((size_t)(b * 64 + s)) * 1024 + col] = f2bf(v);
        } else {
          int s = row & 63, b = row >> 6;
          ((float*)Cout)[((size_t)(s * 128 + b)) * 1024 + col] = v;
        }
      }
    }
  }
}

// ---------- attention A ----------
__global__ __launch_bounds__(256) void attn1_kernel(const u16* __restrict__ qkv,
                                                    u16* __restrict__ am, int seqBase) {
  const int w = threadIdx.x >> 6, l = threadIdx.x & 63;
  const int pair = blockIdx.x * 4 + w;
  const int seq = pair >> 3, head = pair & 7;
  const int d0 = l * 2;
  const u16* base = qkv + (size_t)(seq * 4) * 3072 + head * 128 + d0;
  const float scale = 0.08838834764831845f;
  float q[4][2], k[4][2], v[4][2];
#pragma unroll
  for (int m = 0; m < 4; m++) {
    ushort2 uq = *(const ushort2*)(base + (size_t)m * 3072);
    ushort2 uk = *(const ushort2*)(base + (size_t)m * 3072 + 1024);
    ushort2 uv = *(const ushort2*)(base + (size_t)m * 3072 + 2048);
    q[m][0] = bf2f(uq.x) * scale; q[m][1] = bf2f(uq.y) * scale;
    k[m][0] = bf2f(uk.x);         k[m][1] = bf2f(uk.y);
    v[m][0] = bf2f(uv.x);         v[m][1] = bf2f(uv.y);
  }
  float sc[4][4];
#pragma unroll
  for (int i = 0; i < 4; i++)
#pragma unroll
    for (int j = 0; j < 4; j++)
      sc[i][j] = q[i][0] * k[j][0] + q[i][1] * k[j][1];
#pragma unroll
  for (int off = 32; off >= 1; off >>= 1)
#pragma unroll
    for (int i = 0; i < 4; i++)
#pragma unroll
      for (int j = 0; j < 4; j++)
        sc[i][j] += __shfl_xor(sc[i][j], off, 64);
  float pbar[4] = {0.f, 0.f, 0.f, 0.f};
#pragma unroll
  for (int i = 0; i < 4; i++) {
    float mx = fmaxf(fmaxf(sc[i][0], sc[i][1]), fmaxf(sc[i][2], sc[i][3]));
    float e0 = __expf(sc[i][0] - mx), e1 = __expf(sc[i][1] - mx);
    float e2 = __expf(sc[i][2] - mx), e3 = __expf(sc[i][3] - mx);
    float inv = 0.25f / (e0 + e1 + e2 + e3);
    pbar[0] += e0 * inv; pbar[1] += e1 * inv; pbar[2] += e2 * inv; pbar[3] += e3 * inv;
  }
  float o0 = pbar[0] * v[0][0] + pbar[1] * v[1][0] + pbar[2] * v[2][0] + pbar[3] * v[3][0];
  float o1 = pbar[0] * v[0][1] + pbar[1] * v[1][1] + pbar[2] * v[2][1] + pbar[3] * v[3][1];
  ushort2 ou; ou.x = f2bf(o0); ou.y = f2bf(o1);
  *(ushort2*)(am + (size_t)(seqBase + seq) * 1024 + head * 128 + d0) = ou;
}

// ---------- attention B ----------
__global__ __launch_bounds__(256) void attn2_kernel(const u16* __restrict__ qkv2,
                                                    u16* __restrict__ aout) {
  __shared__ u16 Qs[64 * 128];
  __shared__ u16 Ks[64 * 128];
  __shared__ u16 Vt[128 * 72];
  __shared__ u16 Ps[64 * 72];
  const int t = threadIdx.x, w = t >> 6, l = t & 63;
  const int lr = l & 15, lg = l >> 4;
  const int b = blockIdx.x >> 3, head = blockIdx.x & 7;
  const u16* qb = qkv2 + (size_t)(b * 64) * 3072 + head * 128;

#pragma unroll
  for (int c = 0; c < 4; c++) {
    int flat = c * 256 + t;
    int row = flat >> 4, sp = flat & 15;
    int sg = (sp ^ (row & 7)) * 8;
    GLOAD16(qb + (size_t)row * 3072 + sg, Qs + (c * 256 + w * 64) * 8);
    GLOAD16(qb + 1024 + (size_t)row * 3072 + sg, Ks + (c * 256 + w * 64) * 8);
  }
  const int dd = (t & 63) * 2, kb = t >> 6;
#pragma unroll
  for (int c = 0; c < 16; c++) {
    int k = c * 4 + kb;
    ushort2 vv = *(const ushort2*)(qb + 2048 + (size_t)k * 3072 + dd);
    Vt[(size_t)dd * 72 + k] = vv.x;
    Vt[(size_t)(dd + 1) * 72 + k] = vv.y;
  }
  __syncthreads();

  f32x4 sc[4];
#pragma unroll
  for (int cb = 0; cb < 4; cb++) sc[cb] = (f32x4){0.f, 0.f, 0.f, 0.f};
#pragma unroll
  for (int ks = 0; ks < 4; ks++) {
    bf16x8 aq = *(const bf16x8*)(Qs + (w * 16 + lr) * 128 + ((ks * 4 + lg) ^ (lr & 7)) * 8);
#pragma unroll
    for (int cb = 0; cb < 4; cb++) {
      bf16x8 bk = *(const bf16x8*)(Ks + (cb * 16 + lr) * 128 + ((ks * 4 + lg) ^ (lr & 7)) * 8);
      sc[cb] = __builtin_amdgcn_mfma_f32_16x16x32_bf16(aq, bk, sc[cb], 0, 0, 0);
    }
  }

  const float scale = 0.08838834764831845f;
#pragma unroll
  for (int r = 0; r < 4; r++) {
#pragma unroll
    for (int cb = 0; cb < 4; cb++) sc[cb][r] *= scale;
    float mx = fmaxf(fmaxf(sc[0][r], sc[1][r]), fmaxf(sc[2][r], sc[3][r]));
#pragma unroll
    for (int off = 1; off < 16; off <<= 1) mx = fmaxf(mx, __shfl_xor(mx, off, 64));
    float sum = 0.f;
#pragma unroll
    for (int cb = 0; cb < 4; cb++) {
      float e = __expf(sc[cb][r] - mx);
      sum += e;
      sc[cb][r] = e;
    }
#pragma unroll
    for (int off = 1; off < 16; off <<= 1) sum += __shfl_xor(sum, off, 64);
    float inv = 1.f / sum;
    int prow = w * 16 + lg * 4 + r;
#pragma unroll
    for (int cb = 0; cb < 4; cb++)
      Ps[(size_t)prow * 72 + cb * 16 + lr] = f2bf(sc[cb][r] * inv);
  }

  f32x4 o[8];
#pragma unroll
  for (int cb = 0; cb < 8; cb++) o[cb] = (f32x4){0.f, 0.f, 0.f, 0.f};
#pragma unroll
  for (int ks = 0; ks < 2; ks++) {
    bf16x8 ap = *(const bf16x8*)(Ps + (w * 16 + lr) * 72 + ks * 32 + lg * 8);
#pragma unroll
    for (int cb = 0; cb < 8; cb++) {
      bf16x8 bv = *(const bf16x8*)(Vt + (cb * 16 + lr) * 72 + ks * 32 + lg * 8);
      o[cb] = __builtin_amdgcn_mfma_f32_16x16x32_bf16(ap, bv, o[cb], 0, 0, 0);
    }
  }
#pragma unroll
  for (int cb = 0; cb < 8; cb++) {
#pragma unroll
    for (int r = 0; r < 4; r++) {
      int srow = w * 16 + lg * 4 + r;
      int d = cb * 16 + lr;
      aout[(size_t)(b * 64 + srow) * 1024 + head * 128 + d] = f2bf(o[cb][r]);
    }
  }
}

extern "C" void kernel_launch(void* const* d_in, const int* in_sizes, int n_in,
                              void* d_out, int out_size, void* d_ws, size_t ws_size,
                              hipStream_t stream) {
  const float* hidden   = (const float*)d_in[0];
  const float* mf_in_w  = (const float*)d_in[1];
  const float* mf_in_b  = (const float*)d_in[2];
  const float* mf_out_w = (const float*)d_in[3];
  const float* mf_out_b = (const float*)d_in[4];
  const float* sf_in_w  = (const float*)d_in[5];
  const float* sf_in_b  = (const float*)d_in[6];
  const float* sf_out_w = (const float*)d_in[7];
  const float* sf_out_b = (const float*)d_in[8];
  const float* pos_enc  = (const float*)d_in[9];

  char* ws = (char*)d_ws;
  u16* w_mf_in  = (u16*)(ws);              // 6291456
  u16* w_mf_out = (u16*)(ws + 6291456);    // 2097152
  u16* w_sf_in  = (u16*)(ws + 8388608);    // 6291456
  u16* w_sf_out = (u16*)(ws + 14680064);   // 2097152

  cvtw_kernel<<<3072, 256, 0, stream>>>(mf_in_w, w_mf_in, 786432);
  cvtw_kernel<<<1024, 256, 0, stream>>>(mf_out_w, w_mf_out, 262144);
  cvtw_kernel<<<3072, 256, 0, stream>>>(sf_in_w, w_sf_in, 786432);
  cvtw_kernel<<<1024, 256, 0, stream>>>(sf_out_w, w_sf_out, 262144);

  if (ws_size >= 335544320ull) {
    // full-M path: GEMM1 = one 3072-block dispatch = 6 exact rounds at 2 blocks/CU
    u16* xfull    = (u16*)(ws + 16777216);   // 64 MB
    u16* qkvfull  = (u16*)(ws + 83886080);   // 192 MB
    u16* attnmean = (u16*)(ws + 285212672);  // 16 MB
    u16* seqbuf   = (u16*)(ws + 301989888);  // 16 MB
    u16* a2out    = (u16*)(ws + 318767104);  // 16 MB -> 320 MB total

    xcvt_kernel<<<32768, 256, 0, stream>>>(hidden, xfull, 0);
    gemm_r3<0><<<dim3(24, 128), 256, 0, stream>>>(xfull, w_mf_in, mf_in_b, qkvfull,
                                                  3072, 1024, nullptr);
    attn1_kernel<<<16384, 256, 0, stream>>>(qkvfull, attnmean, 0);

    gemm_r3<1><<<dim3(8, 32), 256, 0, stream>>>(attnmean, w_mf_out, mf_out_b, seqbuf,
                                                1024, 1024, pos_enc);
    gemm_r3<0><<<dim3(24, 32), 256, 0, stream>>>(seqbuf, w_sf_in, sf_in_b, qkvfull,
                                                 3072, 1024, nullptr);
    attn2_kernel<<<1024, 256, 0, stream>>>(qkvfull, a2out);
    gemm_r3<2><<<dim3(8, 32), 256, 0, stream>>>(a2out, w_sf_out, sf_out_b, d_out,
                                                1024, 1024, nullptr);
  } else {
    // chunked fallback (128 MB)
    u16* xchunk   = (u16*)(ws + 16777216);
    u16* qkvbuf   = (u16*)(ws + 33554432);
    u16* attnmean = (u16*)(ws + 83886080);
    u16* seqbuf   = (u16*)(ws + 100663296);
    u16* a2out    = (u16*)(ws + 117440512);

    for (int c = 0; c < 4; ++c) {
      xcvt_kernel<<<8192, 256, 0, stream>>>(hidden, xchunk, c * 16);
      gemm_r3<0><<<dim3(24, 32), 256, 0, stream>>>(xchunk, w_mf_in, mf_in_b, qkvbuf,
                                                   3072, 1024, nullptr);
      attn1_kernel<<<4096, 256, 0, stream>>>(qkvbuf, attnmean, c * 2048);
    }

    gemm_r3<1><<<dim3(8, 32), 256, 0, stream>>>(attnmean, w_mf_out, mf_out_b, seqbuf,
                                                1024, 1024, pos_enc);
    gemm_r3<0><<<dim3(24, 32), 256, 0, stream>>>(seqbuf, w_sf_in, sf_in_b, qkvbuf,
                                                 3072, 1024, nullptr);
    attn2_kernel<<<1024, 256, 0, stream>>>(qkvbuf, a2out);
    gemm_r3<2><<<dim3(8, 32), 256, 0, stream>>>(a2out, w_sf_out, sf_out_b, d_out,
                                                1024, 1024, nullptr);
  }
}

// Round 9
// 474.574 us; speedup vs baseline: 1.0806x; 1.0806x over previous
//
#include <hip/hip_runtime.h>

typedef unsigned short u16;
typedef __attribute__((ext_vector_type(8))) short bf16x8;
typedef __attribute__((ext_vector_type(4))) float f32x4;

__device__ __forceinline__ u16 f2bf(float f) {
  unsigned u = __float_as_uint(f);
  u += 0x7FFFu + ((u >> 16) & 1u);
  return (u16)(u >> 16);
}
__device__ __forceinline__ float bf2f(u16 h) {
  return __uint_as_float(((unsigned)h) << 16);
}

#define GLOAD16(g, l) __builtin_amdgcn_global_load_lds( \
    (const __attribute__((address_space(1))) void*)(g), \
    (__attribute__((address_space(3))) void*)(l), 16, 0, 0)

// ---------- elementwise converts ----------
__global__ __launch_bounds__(256) void cvtw_kernel(const float* __restrict__ in,
                                                   u16* __restrict__ out, int n4) {
  int i = blockIdx.x * 256 + threadIdx.x;
  if (i >= n4) return;
  float4 f = ((const float4*)in)[i];
  ushort4 u;
  u.x = f2bf(f.x); u.y = f2bf(f.y); u.z = f2bf(f.z); u.w = f2bf(f.w);
  ((ushort4*)out)[i] = u;
}

// gather x rows = ((s-s0)*128 + b)*4 + m from hidden[s][m][b][0][h]
// general in chunk size: lrow = 0 .. (rows-1), sl = lrow>>9
__global__ __launch_bounds__(256) void xcvt_kernel(const float* __restrict__ hidden,
                                                   u16* __restrict__ xb, int s0) {
  int idx = blockIdx.x * 256 + threadIdx.x;
  int h4 = idx & 255;
  int lrow = idx >> 8;
  int m = lrow & 3;
  int b = (lrow >> 2) & 127;
  int sl = lrow >> 9;
  int s = s0 + sl;
  const float4 f = *(const float4*)(hidden + (((size_t)(s * 4 + m) * 128 + b) * 1024) + h4 * 4);
  ushort4 u;
  u.x = f2bf(f.x); u.y = f2bf(f.y); u.z = f2bf(f.z); u.w = f2bf(f.w);
  *(ushort4*)(xb + (size_t)lrow * 1024 + h4 * 4) = u;
}

// ---------- 8-phase 256x256 GEMM, BK=64, 8 waves (R7 structure, unchanged) ----------
template <int KK>
__global__ __launch_bounds__(512, 2) void gemm8p(const u16* __restrict__ A,
                                                 const u16* __restrict__ Bw,
                                                 const float* __restrict__ bias,
                                                 u16* __restrict__ C, int N) {
  __shared__ u16 Sh[65536];   // 128 KB
  const int t = threadIdx.x, w = t >> 6, l = t & 63;
  const int lr = l & 15, lg = l >> 4;
  const int wm = w >> 2, wn = w & 3;

  const int gx = gridDim.x;
  const int nb = gx * gridDim.y;
  const int id = blockIdx.y * gx + blockIdx.x;
  const int id2 = (id & 7) * (nb >> 3) + (id >> 3);
  const int rowBase = (id2 / gx) * 256, colBase = (id2 % gx) * 256;

  const int sslot8 = ((t & 3) ^ ((t >> 3) & 3)) * 8;
  const u16* Ag = A + (size_t)(rowBase + (t >> 2)) * KK + sslot8;
  const u16* Bg = Bw + (size_t)(colBase + (t >> 2)) * KK + sslot8;
  const size_t K128 = (size_t)128 * KK;
  const int ldsW = w * 512;

  const int fslot8 = (lg ^ ((lr >> 1) & 3)) * 8;
  const int aRowOff = (wm * 128 + lr) * 32 + fslot8;
  const int bRowOff = (wn * 64 + lr) * 32 + fslot8;

  f32x4 acc[8][4];
#pragma unroll
  for (int i = 0; i < 8; i++)
#pragma unroll
    for (int j = 0; j < 4; j++) acc[i][j] = (f32x4){0.f, 0.f, 0.f, 0.f};
  bf16x8 af[2][4], bfr[2][4];

#define STGA(tt, KH, DB) { \
    const u16* g_ = Ag + (size_t)(tt) * 64 + (KH) * 32; \
    GLOAD16(g_, Sh + ((DB) * 2 + (KH)) * 8192 + ldsW); \
    GLOAD16(g_ + K128, Sh + ((DB) * 2 + (KH)) * 8192 + 4096 + ldsW); }
#define STGB(tt, KH, DB) { \
    const u16* g_ = Bg + (size_t)(tt) * 64 + (KH) * 32; \
    GLOAD16(g_, Sh + 32768 + ((DB) * 2 + (KH)) * 8192 + ldsW); \
    GLOAD16(g_ + K128, Sh + 32768 + ((DB) * 2 + (KH)) * 8192 + 4096 + ldsW); }

#define RA(DD, KH, MG, BUF) { \
    const u16* sa_ = Sh + ((DD) * 2 + (KH)) * 8192 + aRowOff; \
    _Pragma("unroll") \
    for (int mi = 0; mi < 4; mi++) af[BUF][mi] = *(const bf16x8*)(sa_ + ((MG) * 4 + mi) * 512); }
#define RB(DD, KH, BUF) { \
    const u16* sb_ = Sh + 32768 + ((DD) * 2 + (KH)) * 8192 + bRowOff; \
    _Pragma("unroll") \
    for (int n = 0; n < 4; n++) bfr[BUF][n] = *(const bf16x8*)(sb_ + n * 512); }

#define LG(NN) asm volatile("s_waitcnt lgkmcnt(" #NN ")" ::: "memory"); \
               __builtin_amdgcn_sched_barrier(0)
#define WTC(NN) asm volatile("s_waitcnt vmcnt(" #NN ")" ::: "memory")
#define BAR __builtin_amdgcn_s_barrier()

#define MM(MG, AB, BB) { \
    __builtin_amdgcn_s_setprio(1); \
    _Pragma("unroll") \
    for (int mi = 0; mi < 4; mi++) { \
      _Pragma("unroll") \
      for (int n = 0; n < 4; n++) \
        acc[(MG) * 4 + mi][n] = __builtin_amdgcn_mfma_f32_16x16x32_bf16( \
            af[AB][mi], bfr[BB][n], acc[(MG) * 4 + mi][n], 0, 0, 0); \
    } \
    __builtin_amdgcn_s_setprio(0); }

  STGA(0, 0, 0); STGB(0, 0, 0);
  STGA(0, 1, 0); STGB(0, 1, 0);
  STGA(1, 0, 1); STGB(1, 0, 1);
  WTC(8);
  BAR;
  RA(0, 0, 0, 0); RB(0, 0, 0);

  const int NIT = KK / 128;
  int t0 = 0;
  for (int it = 0; it < NIT - 1; ++it, t0 += 2) {
    STGA(t0 + 1, 1, 1); RA(0, 0, 1, 1);              LG(4); MM(0, 0, 0); WTC(6); BAR;
    STGB(t0 + 1, 1, 1); RA(0, 1, 0, 0); RB(0, 1, 1); LG(8); MM(1, 1, 0);         BAR;
    STGA(t0 + 2, 0, 0); RA(0, 1, 1, 1);              LG(4); MM(0, 0, 1); WTC(6); BAR;
    STGB(t0 + 2, 0, 0); RA(1, 0, 0, 0); RB(1, 0, 0); LG(8); MM(1, 1, 1);         BAR;
    STGA(t0 + 2, 1, 0); RA(1, 0, 1, 1);              LG(4); MM(0, 0, 0); WTC(6); BAR;
    STGB(t0 + 2, 1, 0); RA(1, 1, 0, 0); RB(1, 1, 1); LG(8); MM(1, 1, 0);         BAR;
    STGA(t0 + 3, 0, 1); RA(1, 1, 1, 1);              LG(4); MM(0, 0, 1); WTC(6); BAR;
    STGB(t0 + 3, 0, 1); RA(0, 0, 0, 0); RB(0, 0, 0); LG(8); MM(1, 1, 1);         BAR;
  }
  STGA(t0 + 1, 1, 1); RA(0, 0, 1, 1);              LG(4); MM(0, 0, 0); WTC(6); BAR;
  STGB(t0 + 1, 1, 1); RA(0, 1, 0, 0); RB(0, 1, 1); LG(8); MM(1, 1, 0);         BAR;
  RA(0, 1, 1, 1);                                  LG(4); MM(0, 0, 1); WTC(4); BAR;
  RA(1, 0, 0, 0); RB(1, 0, 0);                     LG(8); MM(1, 1, 1);         BAR;
  RA(1, 0, 1, 1);                                  LG(4); MM(0, 0, 0); WTC(0); BAR;
  RA(1, 1, 0, 0); RB(1, 1, 1);                     LG(8); MM(1, 1, 0);         BAR;
  RA(1, 1, 1, 1);                                  LG(4); MM(0, 0, 1);         BAR;
                                                   LG(0); MM(1, 1, 1);
#undef MM
#undef BAR
#undef WTC
#undef LG
#undef RB
#undef RA
#undef STGB
#undef STGA

  const int orow0 = rowBase + wm * 128 + lg * 4;
  const int ocol0 = colBase + wn * 64 + lr;
#pragma unroll
  for (int m = 0; m < 8; m++) {
#pragma unroll
    for (int n = 0; n < 4; n++) {
      const int col = ocol0 + n * 16;
      const float bv = bias[col];
#pragma unroll
      for (int r = 0; r < 4; r++) {
        const int row = orow0 + m * 16 + r;
        C[(size_t)row * N + col] = f2bf(acc[m][n][r] + bv);
      }
    }
  }
}

// ---------- small GEMM (fine-pipelined, BM=256 BN=128 BK=32, ring-3) ----------
template <int MODE>
__global__ __launch_bounds__(256, 2) void gemm_fp(const u16* __restrict__ A,
                                                  const u16* __restrict__ Bw,
                                                  const float* __restrict__ bias,
                                                  void* __restrict__ Cout,
                                                  int N, int K,
                                                  const float* __restrict__ posenc) {
  __shared__ u16 SA[3][8192];
  __shared__ u16 SB[3][4096];
  const int t = threadIdx.x, w = t >> 6, l = t & 63;
  const int lr = l & 15, lg = l >> 4;
  const int wm = w >> 1, wn = w & 1;

  const int gx = gridDim.x;
  const int nb = gx * gridDim.y;
  const int id = blockIdx.y * gx + blockIdx.x;
  const int id2 = (id & 7) * (nb >> 3) + (id >> 3);
  const int rowBase = (id2 / gx) * 256, colBase = (id2 % gx) * 128;

  const int srow = l >> 2;
  const int ssl = ((l & 3) ^ (srow & 3)) * 8;
  const u16* Ag = A + (size_t)(rowBase + w * 16 + srow) * K + ssl;
  const u16* Bg = Bw + (size_t)(colBase + w * 16 + srow) * K + ssl;
  u16* const lA = &SA[0][0] + w * 512;
  u16* const lB = &SB[0][0] + w * 512;

  const int fsw = (lg ^ (lr & 3)) * 8;
  const int aoff = (wm * 128 + lr) * 32 + fsw;
  const int boff = (wn * 64 + lr) * 32 + fsw;

  f32x4 acc[8][4];
#pragma unroll
  for (int i = 0; i < 8; i++)
#pragma unroll
    for (int j = 0; j < 4; j++) acc[i][j] = (f32x4){0.f, 0.f, 0.f, 0.f};

#define STG_P0(tt, bb) do { \
    const size_t ko_ = (size_t)(tt) * 32; \
    GLOAD16(Ag + ko_,                    lA + (bb) * 8192); \
    GLOAD16(Ag + ko_ + (size_t)64 * K,   lA + (bb) * 8192 + 2048); \
    GLOAD16(Ag + ko_ + (size_t)128 * K,  lA + (bb) * 8192 + 4096); \
  } while (0)
#define STG_P1(tt, bb) do { \
    const size_t ko_ = (size_t)(tt) * 32; \
    GLOAD16(Ag + ko_ + (size_t)192 * K,  lA + (bb) * 8192 + 6144); \
    GLOAD16(Bg + ko_,                    lB + (bb) * 4096); \
    GLOAD16(Bg + ko_ + (size_t)64 * K,   lB + (bb) * 4096 + 2048); \
  } while (0)

  const int nt = K >> 5;
  STG_P0(0, 0); STG_P1(0, 0);
  STG_P0(1, 1); STG_P1(1, 1);
  asm volatile("s_waitcnt vmcnt(6)" ::: "memory");
  __builtin_amdgcn_s_barrier();

  int bcur = 0;
  for (int tt = 0; tt < nt; ++tt) {
    const u16* pa = &SA[bcur][0];
    const u16* pb = &SB[bcur][0];
    const int bnext = (bcur + 2 > 2) ? bcur - 1 : bcur + 2;
    bf16x8 af[4], bfr[4];

#pragma unroll
    for (int m = 0; m < 4; m++) af[m] = *(const bf16x8*)(pa + aoff + m * 512);
#pragma unroll
    for (int n = 0; n < 4; n++) bfr[n] = *(const bf16x8*)(pb + boff + n * 512);
    if (tt + 2 < nt) STG_P0(tt + 2, bnext);
    __builtin_amdgcn_s_barrier();
    asm volatile("s_waitcnt lgkmcnt(0)" ::: "memory");
    __builtin_amdgcn_sched_barrier(0);
    __builtin_amdgcn_s_setprio(1);
#pragma unroll
    for (int m = 0; m < 4; m++)
#pragma unroll
      for (int n = 0; n < 4; n++)
        acc[m][n] = __builtin_amdgcn_mfma_f32_16x16x32_bf16(af[m], bfr[n], acc[m][n], 0, 0, 0);
    __builtin_amdgcn_s_setprio(0);
    __builtin_amdgcn_s_barrier();

#pragma unroll
    for (int m = 0; m < 4; m++) af[m] = *(const bf16x8*)(pa + aoff + (m + 4) * 512);
    if (tt + 2 < nt) STG_P1(tt + 2, bnext);
    __builtin_amdgcn_s_barrier();
    asm volatile("s_waitcnt lgkmcnt(0)" ::: "memory");
    __builtin_amdgcn_sched_barrier(0);
    __builtin_amdgcn_s_setprio(1);
#pragma unroll
    for (int m = 0; m < 4; m++)
#pragma unroll
      for (int n = 0; n < 4; n++)
        acc[m + 4][n] = __builtin_amdgcn_mfma_f32_16x16x32_bf16(af[m], bfr[n], acc[m + 4][n], 0, 0, 0);
    __builtin_amdgcn_s_setprio(0);
    if (tt + 2 < nt) {
      asm volatile("s_waitcnt vmcnt(6)" ::: "memory");
    } else if (tt + 1 < nt) {
      asm volatile("s_waitcnt vmcnt(0)" ::: "memory");
    }
    __builtin_amdgcn_s_barrier();
    bcur = (bcur + 1 > 2) ? 0 : bcur + 1;
  }
#undef STG_P0
#undef STG_P1

  const int orow0 = rowBase + wm * 128 + lg * 4;
  const int ocol0 = colBase + wn * 64 + lr;
#pragma unroll
  for (int m = 0; m < 8; m++) {
#pragma unroll
    for (int n = 0; n < 4; n++) {
      const int col = ocol0 + n * 16;
      const float bv = bias[col];
#pragma unroll
      for (int r = 0; r < 4; r++) {
        const int row = orow0 + m * 16 + r;
        float v = acc[m][n][r] + bv;
        if (MODE == 1) {
          int s = row >> 7, b = row & 127;
          v += posenc[s * 1024 + col];
          ((u16*)Cout)[((size_t)(b * 64 + s)) * 1024 + col] = f2bf(v);
        } else {
          int s = row & 63, b = row >> 6;
          ((float*)Cout)[((size_t)(s * 128 + b)) * 1024 + col] = v;
        }
      }
    }
  }
}

// ---------- attention A ----------
__global__ __launch_bounds__(256) void attn1_kernel(const u16* __restrict__ qkv,
                                                    u16* __restrict__ am, int seqBase) {
  const int w = threadIdx.x >> 6, l = threadIdx.x & 63;
  const int pair = blockIdx.x * 4 + w;
  const int seq = pair >> 3, head = pair & 7;
  const int d0 = l * 2;
  const u16* base = qkv + (size_t)(seq * 4) * 3072 + head * 128 + d0;
  const float scale = 0.08838834764831845f;
  float q[4][2], k[4][2], v[4][2];
#pragma unroll
  for (int m = 0; m < 4; m++) {
    ushort2 uq = *(const ushort2*)(base + (size_t)m * 3072);
    ushort2 uk = *(const ushort2*)(base + (size_t)m * 3072 + 1024);
    ushort2 uv = *(const ushort2*)(base + (size_t)m * 3072 + 2048);
    q[m][0] = bf2f(uq.x) * scale; q[m][1] = bf2f(uq.y) * scale;
    k[m][0] = bf2f(uk.x);         k[m][1] = bf2f(uk.y);
    v[m][0] = bf2f(uv.x);         v[m][1] = bf2f(uv.y);
  }
  float sc[4][4];
#pragma unroll
  for (int i = 0; i < 4; i++)
#pragma unroll
    for (int j = 0; j < 4; j++)
      sc[i][j] = q[i][0] * k[j][0] + q[i][1] * k[j][1];
#pragma unroll
  for (int off = 32; off >= 1; off >>= 1)
#pragma unroll
    for (int i = 0; i < 4; i++)
#pragma unroll
      for (int j = 0; j < 4; j++)
        sc[i][j] += __shfl_xor(sc[i][j], off, 64);
  float pbar[4] = {0.f, 0.f, 0.f, 0.f};
#pragma unroll
  for (int i = 0; i < 4; i++) {
    float mx = fmaxf(fmaxf(sc[i][0], sc[i][1]), fmaxf(sc[i][2], sc[i][3]));
    float e0 = __expf(sc[i][0] - mx), e1 = __expf(sc[i][1] - mx);
    float e2 = __expf(sc[i][2] - mx), e3 = __expf(sc[i][3] - mx);
    float inv = 0.25f / (e0 + e1 + e2 + e3);
    pbar[0] += e0 * inv; pbar[1] += e1 * inv; pbar[2] += e2 * inv; pbar[3] += e3 * inv;
  }
  float o0 = pbar[0] * v[0][0] + pbar[1] * v[1][0] + pbar[2] * v[2][0] + pbar[3] * v[3][0];
  float o1 = pbar[0] * v[0][1] + pbar[1] * v[1][1] + pbar[2] * v[2][1] + pbar[3] * v[3][1];
  ushort2 ou; ou.x = f2bf(o0); ou.y = f2bf(o1);
  *(ushort2*)(am + (size_t)(seqBase + seq) * 1024 + head * 128 + d0) = ou;
}

// ---------- attention B ----------
__global__ __launch_bounds__(256) void attn2_kernel(const u16* __restrict__ qkv2,
                                                    u16* __restrict__ aout) {
  __shared__ u16 Qs[64 * 128];
  __shared__ u16 Ks[64 * 128];
  __shared__ u16 Vt[128 * 72];
  __shared__ u16 Ps[64 * 72];
  const int t = threadIdx.x, w = t >> 6, l = t & 63;
  const int lr = l & 15, lg = l >> 4;
  const int b = blockIdx.x >> 3, head = blockIdx.x & 7;
  const u16* qb = qkv2 + (size_t)(b * 64) * 3072 + head * 128;

#pragma unroll
  for (int c = 0; c < 4; c++) {
    int flat = c * 256 + t;
    int row = flat >> 4, sp = flat & 15;
    int sg = (sp ^ (row & 7)) * 8;
    GLOAD16(qb + (size_t)row * 3072 + sg, Qs + (c * 256 + w * 64) * 8);
    GLOAD16(qb + 1024 + (size_t)row * 3072 + sg, Ks + (c * 256 + w * 64) * 8);
  }
  const int dd = (t & 63) * 2, kb = t >> 6;
#pragma unroll
  for (int c = 0; c < 16; c++) {
    int k = c * 4 + kb;
    ushort2 vv = *(const ushort2*)(qb + 2048 + (size_t)k * 3072 + dd);
    Vt[(size_t)dd * 72 + k] = vv.x;
    Vt[(size_t)(dd + 1) * 72 + k] = vv.y;
  }
  __syncthreads();

  f32x4 sc[4];
#pragma unroll
  for (int cb = 0; cb < 4; cb++) sc[cb] = (f32x4){0.f, 0.f, 0.f, 0.f};
#pragma unroll
  for (int ks = 0; ks < 4; ks++) {
    bf16x8 aq = *(const bf16x8*)(Qs + (w * 16 + lr) * 128 + ((ks * 4 + lg) ^ (lr & 7)) * 8);
#pragma unroll
    for (int cb = 0; cb < 4; cb++) {
      bf16x8 bk = *(const bf16x8*)(Ks + (cb * 16 + lr) * 128 + ((ks * 4 + lg) ^ (lr & 7)) * 8);
      sc[cb] = __builtin_amdgcn_mfma_f32_16x16x32_bf16(aq, bk, sc[cb], 0, 0, 0);
    }
  }

  const float scale = 0.08838834764831845f;
#pragma unroll
  for (int r = 0; r < 4; r++) {
#pragma unroll
    for (int cb = 0; cb < 4; cb++) sc[cb][r] *= scale;
    float mx = fmaxf(fmaxf(sc[0][r], sc[1][r]), fmaxf(sc[2][r], sc[3][r]));
#pragma unroll
    for (int off = 1; off < 16; off <<= 1) mx = fmaxf(mx, __shfl_xor(mx, off, 64));
    float sum = 0.f;
#pragma unroll
    for (int cb = 0; cb < 4; cb++) {
      float e = __expf(sc[cb][r] - mx);
      sum += e;
      sc[cb][r] = e;
    }
#pragma unroll
    for (int off = 1; off < 16; off <<= 1) sum += __shfl_xor(sum, off, 64);
    float inv = 1.f / sum;
    int prow = w * 16 + lg * 4 + r;
#pragma unroll
    for (int cb = 0; cb < 4; cb++)
      Ps[(size_t)prow * 72 + cb * 16 + lr] = f2bf(sc[cb][r] * inv);
  }

  f32x4 o[8];
#pragma unroll
  for (int cb = 0; cb < 8; cb++) o[cb] = (f32x4){0.f, 0.f, 0.f, 0.f};
#pragma unroll
  for (int ks = 0; ks < 2; ks++) {
    bf16x8 ap = *(const bf16x8*)(Ps + (w * 16 + lr) * 72 + ks * 32 + lg * 8);
#pragma unroll
    for (int cb = 0; cb < 8; cb++) {
      bf16x8 bv = *(const bf16x8*)(Vt + (cb * 16 + lr) * 72 + ks * 32 + lg * 8);
      o[cb] = __builtin_amdgcn_mfma_f32_16x16x32_bf16(ap, bv, o[cb], 0, 0, 0);
    }
  }
#pragma unroll
  for (int cb = 0; cb < 8; cb++) {
#pragma unroll
    for (int r = 0; r < 4; r++) {
      int srow = w * 16 + lg * 4 + r;
      int d = cb * 16 + lr;
      aout[(size_t)(b * 64 + srow) * 1024 + head * 128 + d] = f2bf(o[cb][r]);
    }
  }
}

extern "C" void kernel_launch(void* const* d_in, const int* in_sizes, int n_in,
                              void* d_out, int out_size, void* d_ws, size_t ws_size,
                              hipStream_t stream) {
  const float* hidden   = (const float*)d_in[0];
  const float* mf_in_w  = (const float*)d_in[1];
  const float* mf_in_b  = (const float*)d_in[2];
  const float* mf_out_w = (const float*)d_in[3];
  const float* mf_out_b = (const float*)d_in[4];
  const float* sf_in_w  = (const float*)d_in[5];
  const float* sf_in_b  = (const float*)d_in[6];
  const float* sf_out_w = (const float*)d_in[7];
  const float* sf_out_b = (const float*)d_in[8];
  const float* pos_enc  = (const float*)d_in[9];

  char* ws = (char*)d_ws;
  u16* w_mf_in  = (u16*)(ws);              // 6291456
  u16* w_mf_out = (u16*)(ws + 6291456);    // 2097152
  u16* w_sf_in  = (u16*)(ws + 8388608);    // 6291456
  u16* w_sf_out = (u16*)(ws + 14680064);   // 2097152

  cvtw_kernel<<<3072, 256, 0, stream>>>(mf_in_w, w_mf_in, 786432);
  cvtw_kernel<<<1024, 256, 0, stream>>>(mf_out_w, w_mf_out, 262144);
  cvtw_kernel<<<3072, 256, 0, stream>>>(sf_in_w, w_sf_in, 786432);
  cvtw_kernel<<<1024, 256, 0, stream>>>(sf_out_w, w_sf_out, 262144);

  if (ws_size >= 201326592ull) {
    // 2-chunk L3-resident pipeline: chunk = 32 s-values = 16384 rows
    // working set per chunk: x 32MB + qkv 96MB + weights 16MB + attnmean 16MB < 256MB L3
    u16* xchunk   = (u16*)(ws + 16777216);   // 32 MB
    u16* qkvbuf   = (u16*)(ws + 50331648);   // 96 MB
    u16* attnmean = (u16*)(ws + 150994944);  // 16 MB
    u16* seqbuf   = (u16*)(ws + 167772160);  // 16 MB
    u16* a2out    = (u16*)(ws + 184549376);  // 16 MB -> 192 MB total

    for (int c = 0; c < 2; ++c) {
      xcvt_kernel<<<16384, 256, 0, stream>>>(hidden, xchunk, c * 32);
      // grid 12x64 = 768 blocks = 3 exact rounds at 1 block/CU
      gemm8p<1024><<<dim3(12, 64), 512, 0, stream>>>(xchunk, w_mf_in, mf_in_b, qkvbuf, 3072);
      // 4096 seqs x 8 heads / 4 waves = 8192 blocks
      attn1_kernel<<<8192, 256, 0, stream>>>(qkvbuf, attnmean, c * 4096);
    }

    gemm_fp<1><<<dim3(8, 32), 256, 0, stream>>>(attnmean, w_mf_out, mf_out_b, seqbuf,
                                                1024, 1024, pos_enc);
    gemm8p<1024><<<dim3(12, 32), 512, 0, stream>>>(seqbuf, w_sf_in, sf_in_b, qkvbuf, 3072);
    attn2_kernel<<<1024, 256, 0, stream>>>(qkvbuf, a2out);
    gemm_fp<2><<<dim3(8, 32), 256, 0, stream>>>(a2out, w_sf_out, sf_out_b, d_out,
                                                1024, 1024, nullptr);
  } else {
    // 4-chunk fallback (128 MB)
    u16* xchunk   = (u16*)(ws + 16777216);
    u16* qkvbuf   = (u16*)(ws + 33554432);
    u16* attnmean = (u16*)(ws + 83886080);
    u16* seqbuf   = (u16*)(ws + 100663296);
    u16* a2out    = (u16*)(ws + 117440512);

    for (int c = 0; c < 4; ++c) {
      xcvt_kernel<<<8192, 256, 0, stream>>>(hidden, xchunk, c * 16);
      gemm8p<1024><<<dim3(12, 32), 512, 0, stream>>>(xchunk, w_mf_in, mf_in_b, qkvbuf, 3072);
      attn1_kernel<<<4096, 256, 0, stream>>>(qkvbuf, attnmean, c * 2048);
    }

    gemm_fp<1><<<dim3(8, 32), 256, 0, stream>>>(attnmean, w_mf_out, mf_out_b, seqbuf,
                                                1024, 1024, pos_enc);
    gemm8p<1024><<<dim3(12, 32), 512, 0, stream>>>(seqbuf, w_sf_in, sf_in_b, qkvbuf, 3072);
    attn2_kernel<<<1024, 256, 0, stream>>>(qkvbuf, a2out);
    gemm_fp<2><<<dim3(8, 32), 256, 0, stream>>>(a2out, w_sf_out, sf_out_b, d_out,
                                                1024, 1024, nullptr);
  }
}

// Round 10
// 466.759 us; speedup vs baseline: 1.0987x; 1.0167x over previous
//
#include <hip/hip_runtime.h>

typedef unsigned short u16;
typedef __attribute__((ext_vector_type(8))) short bf16x8;
typedef __attribute__((ext_vector_type(4))) float f32x4;

__device__ __forceinline__ u16 f2bf(float f) {
  unsigned u = __float_as_uint(f);
  u += 0x7FFFu + ((u >> 16) & 1u);
  return (u16)(u >> 16);
}
__device__ __forceinline__ float bf2f(u16 h) {
  return __uint_as_float(((unsigned)h) << 16);
}

#define GLOAD16(g, l) __builtin_amdgcn_global_load_lds( \
    (const __attribute__((address_space(1))) void*)(g), \
    (__attribute__((address_space(3))) void*)(l), 16, 0, 0)

// ---------- merged weight convert: 4 tensors in one dispatch ----------
__global__ __launch_bounds__(256) void cvtw4_kernel(const float* __restrict__ s0, u16* __restrict__ d0,
                                                    const float* __restrict__ s1, u16* __restrict__ d1,
                                                    const float* __restrict__ s2, u16* __restrict__ d2,
                                                    const float* __restrict__ s3, u16* __restrict__ d3) {
  int i = blockIdx.x * 256 + threadIdx.x;   // 0 .. 2097151 (float4 units)
  const float* s; u16* d; int off;
  if (i < 786432)       { s = s0; d = d0; off = i; }
  else if (i < 1048576) { s = s1; d = d1; off = i - 786432; }
  else if (i < 1835008) { s = s2; d = d2; off = i - 1048576; }
  else                  { s = s3; d = d3; off = i - 1835008; }
  float4 f = ((const float4*)s)[off];
  ushort4 u;
  u.x = f2bf(f.x); u.y = f2bf(f.y); u.z = f2bf(f.z); u.w = f2bf(f.w);
  ((ushort4*)d)[off] = u;
}

// gather x rows = ((s-s0)*128 + b)*4 + m from hidden[s][m][b][0][h]
__global__ __launch_bounds__(256) void xcvt_kernel(const float* __restrict__ hidden,
                                                   u16* __restrict__ xb, int s0) {
  int idx = blockIdx.x * 256 + threadIdx.x;
  int h4 = idx & 255;
  int lrow = idx >> 8;
  int m = lrow & 3;
  int b = (lrow >> 2) & 127;
  int sl = lrow >> 9;
  int s = s0 + sl;
  const float4 f = *(const float4*)(hidden + (((size_t)(s * 4 + m) * 128 + b) * 1024) + h4 * 4);
  ushort4 u;
  u.x = f2bf(f.x); u.y = f2bf(f.y); u.z = f2bf(f.z); u.w = f2bf(f.w);
  *(ushort4*)(xb + (size_t)lrow * 1024 + h4 * 4) = u;
}

// ---------- 8-phase 256x256 GEMM, BK=64, 8 waves; RAW-ASM barriers ----------
// (R7 schedule; the only change is s_barrier emitted as opaque inline asm so
//  the compiler cannot attach an implicit vmcnt(0)/lgkmcnt(0) drain to it.)
template <int KK>
__global__ __launch_bounds__(512, 2) void gemm8p(const u16* __restrict__ A,
                                                 const u16* __restrict__ Bw,
                                                 const float* __restrict__ bias,
                                                 u16* __restrict__ C, int N) {
  __shared__ u16 Sh[65536];   // 128 KB
  const int t = threadIdx.x, w = t >> 6, l = t & 63;
  const int lr = l & 15, lg = l >> 4;
  const int wm = w >> 2, wn = w & 3;

  const int gx = gridDim.x;
  const int nb = gx * gridDim.y;
  const int id = blockIdx.y * gx + blockIdx.x;
  const int id2 = (id & 7) * (nb >> 3) + (id >> 3);
  const int rowBase = (id2 / gx) * 256, colBase = (id2 % gx) * 256;

  const int sslot8 = ((t & 3) ^ ((t >> 3) & 3)) * 8;
  const u16* Ag = A + (size_t)(rowBase + (t >> 2)) * KK + sslot8;
  const u16* Bg = Bw + (size_t)(colBase + (t >> 2)) * KK + sslot8;
  const size_t K128 = (size_t)128 * KK;
  const int ldsW = w * 512;

  const int fslot8 = (lg ^ ((lr >> 1) & 3)) * 8;
  const int aRowOff = (wm * 128 + lr) * 32 + fslot8;
  const int bRowOff = (wn * 64 + lr) * 32 + fslot8;

  f32x4 acc[8][4];
#pragma unroll
  for (int i = 0; i < 8; i++)
#pragma unroll
    for (int j = 0; j < 4; j++) acc[i][j] = (f32x4){0.f, 0.f, 0.f, 0.f};
  bf16x8 af[2][4], bfr[2][4];

#define STGA(tt, KH, DB) { \
    const u16* g_ = Ag + (size_t)(tt) * 64 + (KH) * 32; \
    GLOAD16(g_, Sh + ((DB) * 2 + (KH)) * 8192 + ldsW); \
    GLOAD16(g_ + K128, Sh + ((DB) * 2 + (KH)) * 8192 + 4096 + ldsW); }
#define STGB(tt, KH, DB) { \
    const u16* g_ = Bg + (size_t)(tt) * 64 + (KH) * 32; \
    GLOAD16(g_, Sh + 32768 + ((DB) * 2 + (KH)) * 8192 + ldsW); \
    GLOAD16(g_ + K128, Sh + 32768 + ((DB) * 2 + (KH)) * 8192 + 4096 + ldsW); }

#define RA(DD, KH, MG, BUF) { \
    const u16* sa_ = Sh + ((DD) * 2 + (KH)) * 8192 + aRowOff; \
    _Pragma("unroll") \
    for (int mi = 0; mi < 4; mi++) af[BUF][mi] = *(const bf16x8*)(sa_ + ((MG) * 4 + mi) * 512); }
#define RB(DD, KH, BUF) { \
    const u16* sb_ = Sh + 32768 + ((DD) * 2 + (KH)) * 8192 + bRowOff; \
    _Pragma("unroll") \
    for (int n = 0; n < 4; n++) bfr[BUF][n] = *(const bf16x8*)(sb_ + n * 512); }

#define LG(NN) asm volatile("s_waitcnt lgkmcnt(" #NN ")" ::: "memory"); \
               __builtin_amdgcn_sched_barrier(0)
#define WTC(NN) asm volatile("s_waitcnt vmcnt(" #NN ")" ::: "memory")
#define BAR asm volatile("s_barrier" ::: "memory")

#define MM(MG, AB, BB) { \
    __builtin_amdgcn_s_setprio(1); \
    _Pragma("unroll") \
    for (int mi = 0; mi < 4; mi++) { \
      _Pragma("unroll") \
      for (int n = 0; n < 4; n++) \
        acc[(MG) * 4 + mi][n] = __builtin_amdgcn_mfma_f32_16x16x32_bf16( \
            af[AB][mi], bfr[BB][n], acc[(MG) * 4 + mi][n], 0, 0, 0); \
    } \
    __builtin_amdgcn_s_setprio(0); }

  // prologue: stage K0 (both halves) + K1.kh0 (12 loads); force K0.kh0 (leave 8)
  STGA(0, 0, 0); STGB(0, 0, 0);
  STGA(0, 1, 0); STGB(0, 1, 0);
  STGA(1, 0, 1); STGB(1, 0, 1);
  WTC(8);
  BAR;
  RA(0, 0, 0, 0); RB(0, 0, 0);

  const int NIT = KK / 128;
  int t0 = 0;
  for (int it = 0; it < NIT - 1; ++it, t0 += 2) {
    STGA(t0 + 1, 1, 1); RA(0, 0, 1, 1);              LG(4); MM(0, 0, 0); WTC(6); BAR;
    STGB(t0 + 1, 1, 1); RA(0, 1, 0, 0); RB(0, 1, 1); LG(8); MM(1, 1, 0);         BAR;
    STGA(t0 + 2, 0, 0); RA(0, 1, 1, 1);              LG(4); MM(0, 0, 1); WTC(6); BAR;
    STGB(t0 + 2, 0, 0); RA(1, 0, 0, 0); RB(1, 0, 0); LG(8); MM(1, 1, 1);         BAR;
    STGA(t0 + 2, 1, 0); RA(1, 0, 1, 1);              LG(4); MM(0, 0, 0); WTC(6); BAR;
    STGB(t0 + 2, 1, 0); RA(1, 1, 0, 0); RB(1, 1, 1); LG(8); MM(1, 1, 0);         BAR;
    STGA(t0 + 3, 0, 1); RA(1, 1, 1, 1);              LG(4); MM(0, 0, 1); WTC(6); BAR;
    STGB(t0 + 3, 0, 1); RA(0, 0, 0, 0); RB(0, 0, 0); LG(8); MM(1, 1, 1);         BAR;
  }
  // peeled last iteration: stage only (t0+1).kh1; drain vmcnt 6/4/0
  STGA(t0 + 1, 1, 1); RA(0, 0, 1, 1);              LG(4); MM(0, 0, 0); WTC(6); BAR;
  STGB(t0 + 1, 1, 1); RA(0, 1, 0, 0); RB(0, 1, 1); LG(8); MM(1, 1, 0);         BAR;
  RA(0, 1, 1, 1);                                  LG(4); MM(0, 0, 1); WTC(4); BAR;
  RA(1, 0, 0, 0); RB(1, 0, 0);                     LG(8); MM(1, 1, 1);         BAR;
  RA(1, 0, 1, 1);                                  LG(4); MM(0, 0, 0); WTC(0); BAR;
  RA(1, 1, 0, 0); RB(1, 1, 1);                     LG(8); MM(1, 1, 0);         BAR;
  RA(1, 1, 1, 1);                                  LG(4); MM(0, 0, 1);         BAR;
                                                   LG(0); MM(1, 1, 1);
#undef MM
#undef BAR
#undef WTC
#undef LG
#undef RB
#undef RA
#undef STGB
#undef STGA

  const int orow0 = rowBase + wm * 128 + lg * 4;
  const int ocol0 = colBase + wn * 64 + lr;
#pragma unroll
  for (int m = 0; m < 8; m++) {
#pragma unroll
    for (int n = 0; n < 4; n++) {
      const int col = ocol0 + n * 16;
      const float bv = bias[col];
#pragma unroll
      for (int r = 0; r < 4; r++) {
        const int row = orow0 + m * 16 + r;
        C[(size_t)row * N + col] = f2bf(acc[m][n][r] + bv);
      }
    }
  }
}

// ---------- small GEMM (fine-pipelined, BM=256 BN=128 BK=32, ring-3; raw-asm barriers) ----------
template <int MODE>
__global__ __launch_bounds__(256, 2) void gemm_fp(const u16* __restrict__ A,
                                                  const u16* __restrict__ Bw,
                                                  const float* __restrict__ bias,
                                                  void* __restrict__ Cout,
                                                  int N, int K,
                                                  const float* __restrict__ posenc) {
  __shared__ u16 SA[3][8192];
  __shared__ u16 SB[3][4096];
  const int t = threadIdx.x, w = t >> 6, l = t & 63;
  const int lr = l & 15, lg = l >> 4;
  const int wm = w >> 1, wn = w & 1;

  const int gx = gridDim.x;
  const int nb = gx * gridDim.y;
  const int id = blockIdx.y * gx + blockIdx.x;
  const int id2 = (id & 7) * (nb >> 3) + (id >> 3);
  const int rowBase = (id2 / gx) * 256, colBase = (id2 % gx) * 128;

  const int srow = l >> 2;
  const int ssl = ((l & 3) ^ (srow & 3)) * 8;
  const u16* Ag = A + (size_t)(rowBase + w * 16 + srow) * K + ssl;
  const u16* Bg = Bw + (size_t)(colBase + w * 16 + srow) * K + ssl;
  u16* const lA = &SA[0][0] + w * 512;
  u16* const lB = &SB[0][0] + w * 512;

  const int fsw = (lg ^ (lr & 3)) * 8;
  const int aoff = (wm * 128 + lr) * 32 + fsw;
  const int boff = (wn * 64 + lr) * 32 + fsw;

  f32x4 acc[8][4];
#pragma unroll
  for (int i = 0; i < 8; i++)
#pragma unroll
    for (int j = 0; j < 4; j++) acc[i][j] = (f32x4){0.f, 0.f, 0.f, 0.f};

#define STG_P0(tt, bb) do { \
    const size_t ko_ = (size_t)(tt) * 32; \
    GLOAD16(Ag + ko_,                    lA + (bb) * 8192); \
    GLOAD16(Ag + ko_ + (size_t)64 * K,   lA + (bb) * 8192 + 2048); \
    GLOAD16(Ag + ko_ + (size_t)128 * K,  lA + (bb) * 8192 + 4096); \
  } while (0)
#define STG_P1(tt, bb) do { \
    const size_t ko_ = (size_t)(tt) * 32; \
    GLOAD16(Ag + ko_ + (size_t)192 * K,  lA + (bb) * 8192 + 6144); \
    GLOAD16(Bg + ko_,                    lB + (bb) * 4096); \
    GLOAD16(Bg + ko_ + (size_t)64 * K,   lB + (bb) * 4096 + 2048); \
  } while (0)
#define FBAR asm volatile("s_barrier" ::: "memory")

  const int nt = K >> 5;
  STG_P0(0, 0); STG_P1(0, 0);
  STG_P0(1, 1); STG_P1(1, 1);
  asm volatile("s_waitcnt vmcnt(6)" ::: "memory");
  FBAR;

  int bcur = 0;
  for (int tt = 0; tt < nt; ++tt) {
    const u16* pa = &SA[bcur][0];
    const u16* pb = &SB[bcur][0];
    const int bnext = (bcur + 2 > 2) ? bcur - 1 : bcur + 2;
    bf16x8 af[4], bfr[4];

#pragma unroll
    for (int m = 0; m < 4; m++) af[m] = *(const bf16x8*)(pa + aoff + m * 512);
#pragma unroll
    for (int n = 0; n < 4; n++) bfr[n] = *(const bf16x8*)(pb + boff + n * 512);
    if (tt + 2 < nt) STG_P0(tt + 2, bnext);
    FBAR;
    asm volatile("s_waitcnt lgkmcnt(0)" ::: "memory");
    __builtin_amdgcn_sched_barrier(0);
    __builtin_amdgcn_s_setprio(1);
#pragma unroll
    for (int m = 0; m < 4; m++)
#pragma unroll
      for (int n = 0; n < 4; n++)
        acc[m][n] = __builtin_amdgcn_mfma_f32_16x16x32_bf16(af[m], bfr[n], acc[m][n], 0, 0, 0);
    __builtin_amdgcn_s_setprio(0);
    FBAR;

#pragma unroll
    for (int m = 0; m < 4; m++) af[m] = *(const bf16x8*)(pa + aoff + (m + 4) * 512);
    if (tt + 2 < nt) STG_P1(tt + 2, bnext);
    FBAR;
    asm volatile("s_waitcnt lgkmcnt(0)" ::: "memory");
    __builtin_amdgcn_sched_barrier(0);
    __builtin_amdgcn_s_setprio(1);
#pragma unroll
    for (int m = 0; m < 4; m++)
#pragma unroll
      for (int n = 0; n < 4; n++)
        acc[m + 4][n] = __builtin_amdgcn_mfma_f32_16x16x32_bf16(af[m], bfr[n], acc[m + 4][n], 0, 0, 0);
    __builtin_amdgcn_s_setprio(0);
    if (tt + 2 < nt) {
      asm volatile("s_waitcnt vmcnt(6)" ::: "memory");
    } else if (tt + 1 < nt) {
      asm volatile("s_waitcnt vmcnt(0)" ::: "memory");
    }
    FBAR;
    bcur = (bcur + 1 > 2) ? 0 : bcur + 1;
  }
#undef FBAR
#undef STG_P0
#undef STG_P1

  const int orow0 = rowBase + wm * 128 + lg * 4;
  const int ocol0 = colBase + wn * 64 + lr;
#pragma unroll
  for (int m = 0; m < 8; m++) {
#pragma unroll
    for (int n = 0; n < 4; n++) {
      const int col = ocol0 + n * 16;
      const float bv = bias[col];
#pragma unroll
      for (int r = 0; r < 4; r++) {
        const int row = orow0 + m * 16 + r;
        float v = acc[m][n][r] + bv;
        if (MODE == 1) {
          int s = row >> 7, b = row & 127;
          v += posenc[s * 1024 + col];
          ((u16*)Cout)[((size_t)(b * 64 + s)) * 1024 + col] = f2bf(v);
        } else {
          int s = row & 63, b = row >> 6;
          ((float*)Cout)[((size_t)(s * 128 + b)) * 1024 + col] = v;
        }
      }
    }
  }
}

// ---------- attention A ----------
__global__ __launch_bounds__(256) void attn1_kernel(const u16* __restrict__ qkv,
                                                    u16* __restrict__ am, int seqBase) {
  const int w = threadIdx.x >> 6, l = threadIdx.x & 63;
  const int pair = blockIdx.x * 4 + w;
  const int seq = pair >> 3, head = pair & 7;
  const int d0 = l * 2;
  const u16* base = qkv + (size_t)(seq * 4) * 3072 + head * 128 + d0;
  const float scale = 0.08838834764831845f;
  float q[4][2], k[4][2], v[4][2];
#pragma unroll
  for (int m = 0; m < 4; m++) {
    ushort2 uq = *(const ushort2*)(base + (size_t)m * 3072);
    ushort2 uk = *(const ushort2*)(base + (size_t)m * 3072 + 1024);
    ushort2 uv = *(const ushort2*)(base + (size_t)m * 3072 + 2048);
    q[m][0] = bf2f(uq.x) * scale; q[m][1] = bf2f(uq.y) * scale;
    k[m][0] = bf2f(uk.x);         k[m][1] = bf2f(uk.y);
    v[m][0] = bf2f(uv.x);         v[m][1] = bf2f(uv.y);
  }
  float sc[4][4];
#pragma unroll
  for (int i = 0; i < 4; i++)
#pragma unroll
    for (int j = 0; j < 4; j++)
      sc[i][j] = q[i][0] * k[j][0] + q[i][1] * k[j][1];
#pragma unroll
  for (int off = 32; off >= 1; off >>= 1)
#pragma unroll
    for (int i = 0; i < 4; i++)
#pragma unroll
      for (int j = 0; j < 4; j++)
        sc[i][j] += __shfl_xor(sc[i][j], off, 64);
  float pbar[4] = {0.f, 0.f, 0.f, 0.f};
#pragma unroll
  for (int i = 0; i < 4; i++) {
    float mx = fmaxf(fmaxf(sc[i][0], sc[i][1]), fmaxf(sc[i][2], sc[i][3]));
    float e0 = __expf(sc[i][0] - mx), e1 = __expf(sc[i][1] - mx);
    float e2 = __expf(sc[i][2] - mx), e3 = __expf(sc[i][3] - mx);
    float inv = 0.25f / (e0 + e1 + e2 + e3);
    pbar[0] += e0 * inv; pbar[1] += e1 * inv; pbar[2] += e2 * inv; pbar[3] += e3 * inv;
  }
  float o0 = pbar[0] * v[0][0] + pbar[1] * v[1][0] + pbar[2] * v[2][0] + pbar[3] * v[3][0];
  float o1 = pbar[0] * v[0][1] + pbar[1] * v[1][1] + pbar[2] * v[2][1] + pbar[3] * v[3][1];
  ushort2 ou; ou.x = f2bf(o0); ou.y = f2bf(o1);
  *(ushort2*)(am + (size_t)(seqBase + seq) * 1024 + head * 128 + d0) = ou;
}

// ---------- attention B ----------
__global__ __launch_bounds__(256) void attn2_kernel(const u16* __restrict__ qkv2,
                                                    u16* __restrict__ aout) {
  __shared__ u16 Qs[64 * 128];
  __shared__ u16 Ks[64 * 128];
  __shared__ u16 Vt[128 * 72];
  __shared__ u16 Ps[64 * 72];
  const int t = threadIdx.x, w = t >> 6, l = t & 63;
  const int lr = l & 15, lg = l >> 4;
  const int b = blockIdx.x >> 3, head = blockIdx.x & 7;
  const u16* qb = qkv2 + (size_t)(b * 64) * 3072 + head * 128;

#pragma unroll
  for (int c = 0; c < 4; c++) {
    int flat = c * 256 + t;
    int row = flat >> 4, sp = flat & 15;
    int sg = (sp ^ (row & 7)) * 8;
    GLOAD16(qb + (size_t)row * 3072 + sg, Qs + (c * 256 + w * 64) * 8);
    GLOAD16(qb + 1024 + (size_t)row * 3072 + sg, Ks + (c * 256 + w * 64) * 8);
  }
  const int dd = (t & 63) * 2, kb = t >> 6;
#pragma unroll
  for (int c = 0; c < 16; c++) {
    int k = c * 4 + kb;
    ushort2 vv = *(const ushort2*)(qb + 2048 + (size_t)k * 3072 + dd);
    Vt[(size_t)dd * 72 + k] = vv.x;
    Vt[(size_t)(dd + 1) * 72 + k] = vv.y;
  }
  __syncthreads();

  f32x4 sc[4];
#pragma unroll
  for (int cb = 0; cb < 4; cb++) sc[cb] = (f32x4){0.f, 0.f, 0.f, 0.f};
#pragma unroll
  for (int ks = 0; ks < 4; ks++) {
    bf16x8 aq = *(const bf16x8*)(Qs + (w * 16 + lr) * 128 + ((ks * 4 + lg) ^ (lr & 7)) * 8);
#pragma unroll
    for (int cb = 0; cb < 4; cb++) {
      bf16x8 bk = *(const bf16x8*)(Ks + (cb * 16 + lr) * 128 + ((ks * 4 + lg) ^ (lr & 7)) * 8);
      sc[cb] = __builtin_amdgcn_mfma_f32_16x16x32_bf16(aq, bk, sc[cb], 0, 0, 0);
    }
  }

  const float scale = 0.08838834764831845f;
#pragma unroll
  for (int r = 0; r < 4; r++) {
#pragma unroll
    for (int cb = 0; cb < 4; cb++) sc[cb][r] *= scale;
    float mx = fmaxf(fmaxf(sc[0][r], sc[1][r]), fmaxf(sc[2][r], sc[3][r]));
#pragma unroll
    for (int off = 1; off < 16; off <<= 1) mx = fmaxf(mx, __shfl_xor(mx, off, 64));
    float sum = 0.f;
#pragma unroll
    for (int cb = 0; cb < 4; cb++) {
      float e = __expf(sc[cb][r] - mx);
      sum += e;
      sc[cb][r] = e;
    }
#pragma unroll
    for (int off = 1; off < 16; off <<= 1) sum += __shfl_xor(sum, off, 64);
    float inv = 1.f / sum;
    int prow = w * 16 + lg * 4 + r;
#pragma unroll
    for (int cb = 0; cb < 4; cb++)
      Ps[(size_t)prow * 72 + cb * 16 + lr] = f2bf(sc[cb][r] * inv);
  }

  f32x4 o[8];
#pragma unroll
  for (int cb = 0; cb < 8; cb++) o[cb] = (f32x4){0.f, 0.f, 0.f, 0.f};
#pragma unroll
  for (int ks = 0; ks < 2; ks++) {
    bf16x8 ap = *(const bf16x8*)(Ps + (w * 16 + lr) * 72 + ks * 32 + lg * 8);
#pragma unroll
    for (int cb = 0; cb < 8; cb++) {
      bf16x8 bv = *(const bf16x8*)(Vt + (cb * 16 + lr) * 72 + ks * 32 + lg * 8);
      o[cb] = __builtin_amdgcn_mfma_f32_16x16x32_bf16(ap, bv, o[cb], 0, 0, 0);
    }
  }
#pragma unroll
  for (int cb = 0; cb < 8; cb++) {
#pragma unroll
    for (int r = 0; r < 4; r++) {
      int srow = w * 16 + lg * 4 + r;
      int d = cb * 16 + lr;
      aout[(size_t)(b * 64 + srow) * 1024 + head * 128 + d] = f2bf(o[cb][r]);
    }
  }
}

extern "C" void kernel_launch(void* const* d_in, const int* in_sizes, int n_in,
                              void* d_out, int out_size, void* d_ws, size_t ws_size,
                              hipStream_t stream) {
  const float* hidden   = (const float*)d_in[0];
  const float* mf_in_w  = (const float*)d_in[1];
  const float* mf_in_b  = (const float*)d_in[2];
  const float* mf_out_w = (const float*)d_in[3];
  const float* mf_out_b = (const float*)d_in[4];
  const float* sf_in_w  = (const float*)d_in[5];
  const float* sf_in_b  = (const float*)d_in[6];
  const float* sf_out_w = (const float*)d_in[7];
  const float* sf_out_b = (const float*)d_in[8];
  const float* pos_enc  = (const float*)d_in[9];

  char* ws = (char*)d_ws;
  u16* w_mf_in  = (u16*)(ws);              // 6291456
  u16* w_mf_out = (u16*)(ws + 6291456);    // 2097152
  u16* w_sf_in  = (u16*)(ws + 8388608);    // 6291456
  u16* w_sf_out = (u16*)(ws + 14680064);   // 2097152

  cvtw4_kernel<<<8192, 256, 0, stream>>>(mf_in_w, w_mf_in, mf_out_w, w_mf_out,
                                         sf_in_w, w_sf_in, sf_out_w, w_sf_out);

  if (ws_size >= 201326592ull) {
    // 2-chunk pipeline (chunk = 32 s-values = 16384 rows)
    u16* xchunk   = (u16*)(ws + 16777216);   // 32 MB
    u16* qkvbuf   = (u16*)(ws + 50331648);   // 96 MB
    u16* attnmean = (u16*)(ws + 150994944);  // 16 MB
    u16* seqbuf   = (u16*)(ws + 167772160);  // 16 MB
    u16* a2out    = (u16*)(ws + 184549376);  // 16 MB -> 192 MB total

    for (int c = 0; c < 2; ++c) {
      xcvt_kernel<<<16384, 256, 0, stream>>>(hidden, xchunk, c * 32);
      gemm8p<1024><<<dim3(12, 64), 512, 0, stream>>>(xchunk, w_mf_in, mf_in_b, qkvbuf, 3072);
      attn1_kernel<<<8192, 256, 0, stream>>>(qkvbuf, attnmean, c * 4096);
    }

    gemm_fp<1><<<dim3(8, 32), 256, 0, stream>>>(attnmean, w_mf_out, mf_out_b, seqbuf,
                                                1024, 1024, pos_enc);
    gemm8p<1024><<<dim3(12, 32), 512, 0, stream>>>(seqbuf, w_sf_in, sf_in_b, qkvbuf, 3072);
    attn2_kernel<<<1024, 256, 0, stream>>>(qkvbuf, a2out);
    gemm_fp<2><<<dim3(8, 32), 256, 0, stream>>>(a2out, w_sf_out, sf_out_b, d_out,
                                                1024, 1024, nullptr);
  } else {
    // 4-chunk fallback (128 MB)
    u16* xchunk   = (u16*)(ws + 16777216);
    u16* qkvbuf   = (u16*)(ws + 33554432);
    u16* attnmean = (u16*)(ws + 83886080);
    u16* seqbuf   = (u16*)(ws + 100663296);
    u16* a2out    = (u16*)(ws + 117440512);

    for (int c = 0; c < 4; ++c) {
      xcvt_kernel<<<8192, 256, 0, stream>>>(hidden, xchunk, c * 16);
      gemm8p<1024><<<dim3(12, 32), 512, 0, stream>>>(xchunk, w_mf_in, mf_in_b, qkvbuf, 3072);
      attn1_kernel<<<4096, 256, 0, stream>>>(qkvbuf, attnmean, c * 2048);
    }

    gemm_fp<1><<<dim3(8, 32), 256, 0, stream>>>(attnmean, w_mf_out, mf_out_b, seqbuf,
                                                1024, 1024, pos_enc);
    gemm8p<1024><<<dim3(12, 32), 512, 0, stream>>>(seqbuf, w_sf_in, sf_in_b, qkvbuf, 3072);
    attn2_kernel<<<1024, 256, 0, stream>>>(qkvbuf, a2out);
    gemm_fp<2><<<dim3(8, 32), 256, 0, stream>>>(a2out, w_sf_out, sf_out_b, d_out,
                                                1024, 1024, nullptr);
  }
}